// Round 6
// baseline (242.542 us; speedup 1.0000x reference)
//
#include <hip/hip_runtime.h>

#define N_ATOMS 2048
#define NSPEC 7
#define NR 16
#define NFEAT 112          // 7 species * 16 radial shifts; aev[112:1008] is zero padding
#define RCR_F 5.2f
#define H0 256
#define H1 192
#define H2 160
#define W0_PITCH 1008      // W0 rows are 1008 wide; only first 112 columns matter
#define TILE 8             // atoms per MLP block
#define NTILES (N_ATOMS / TILE)

// ---- workspace layout (byte offsets into d_ws) ----
#define WS_SEG     0         // int[8] species segment starts (seg[7] = N)
#define WS_SCOORD  16384     // float4[2048] species-sorted coordinates
#define WS_AEV     65536     // float[2048*112]
#define WS_H0BUF   1048576   // float[2048*256]
#define WS_H1BUF   3145728   // float[2048*192]

__device__ __forceinline__ float celu01(float x) {
    return x > 0.f ? x : 0.1f * (__expf(x * 10.f) - 1.f);
}

// ---------------- K0: counting sort by species + init ----------------
__global__ __launch_bounds__(256) void sort_kernel(const int* __restrict__ species,
                                                   const float* __restrict__ coords,
                                                   int* __restrict__ seg,
                                                   float4* __restrict__ scoord,
                                                   float* __restrict__ out) {
    __shared__ int cnt[NSPEC];
    __shared__ int cur[NSPEC];
    int t = threadIdx.x;
    if (t < NSPEC) cnt[t] = 0;
    __syncthreads();
    for (int a = t; a < N_ATOMS; a += 256) atomicAdd(&cnt[species[a]], 1);
    __syncthreads();
    if (t == 0) {
        int run = 0;
        for (int s = 0; s < NSPEC; s++) { seg[s] = run; cur[s] = run; run += cnt[s]; }
        seg[NSPEC] = run;
        out[0] = 0.0f;   // d_out is poisoned before every call
    }
    __syncthreads();
    for (int a = t; a < N_ATOMS; a += 256) {
        int sp = species[a];
        int pos = atomicAdd(&cur[sp], 1);
        scoord[pos] = make_float4(coords[3*a], coords[3*a+1], coords[3*a+2], 0.f);
    }
}

// ---------------- K1: pair-parallel radial AEV (unchanged from R5) ----------------
__global__ __launch_bounds__(256) void aev_kernel(const float4* __restrict__ scoord,
                                                  const int* __restrict__ seg,
                                                  const float* __restrict__ ShfR,
                                                  const float* __restrict__ EtaR,
                                                  float* __restrict__ aev) {
    int s = blockIdx.y;
    int p = blockIdx.x * 4 + (threadIdx.x >> 6);
    int lane = threadIdx.x & 63;

    float4 ci = scoord[p];
    float eta = EtaR[0];
    float shf[NR];
#pragma unroll
    for (int r = 0; r < NR; r++) shf[r] = ShfR[r];   // uniform -> SGPRs
    float acc[NR];
#pragma unroll
    for (int r = 0; r < NR; r++) acc[r] = 0.f;

    int kbeg = seg[s] + lane;
    int kend = seg[s + 1];
    const float rc2 = RCR_F * RCR_F;
    const float cosk = 3.14159265358979f / RCR_F;

    for (int k = kbeg; k < kend; k += 64) {
        float4 cj = scoord[k];
        float dx = ci.x - cj.x, dy = ci.y - cj.y, dz = ci.z - cj.z;
        float dsq = dx*dx + dy*dy + dz*dz;
        bool valid = (dsq > 0.f) && (dsq <= rc2);   // excludes self (d==0)
        float d = sqrtf(dsq);
        float fc = 0.5f * __cosf(d * cosk) + 0.5f;
        fc = valid ? fc : 0.f;
#pragma unroll
        for (int r = 0; r < NR; r++) {
            float u = d - shf[r];
            acc[r] = fmaf(__expf(-eta * u * u), fc, acc[r]);  // underflow -> 0, matches ref
        }
    }
#pragma unroll
    for (int r = 0; r < NR; r++) {
        float v = acc[r];
        v += __shfl_xor(v, 1);
        v += __shfl_xor(v, 2);
        v += __shfl_xor(v, 4);
        v += __shfl_xor(v, 8);
        v += __shfl_xor(v, 16);
        v += __shfl_xor(v, 32);
        acc[r] = v;
    }
    if (lane == 0) {
        float* dst = aev + (size_t)p * NFEAT + s * NR;
#pragma unroll
        for (int r = 0; r < NR; r += 4)
            *(float4*)(dst + r) = make_float4(acc[r], acc[r+1], acc[r+2], acc[r+3]);
    }
}

// ================= MLP layers: NO LDS =================
// Grid (NTILES, NSPEC); thread t = o*4 + ks. Activations read straight from
// global: a wave's 64 lanes touch only 4 consecutive float4s (one 64B
// segment -> single coalesced VMEM, L2-served) instead of the ds_read
// broadcast storm that made R5's fused kernel LDS-issue-bound (~560
// ds_read_b128/wave @ ~12cyc on one LDS pipe = ~22us/CU). All loop bounds
// compile-time -> acc[] stays in VGPRs. Out-of-tile reads (q >= n_act) hit
// valid ws memory and are discarded by the store predicate.

// ---------------- K2a: layer0  aev[112] -> h0[256], 1024 thr ----------------
__global__ __launch_bounds__(1024) void mlp0_kernel(const float* __restrict__ W0,
                                                    const float* __restrict__ b0,
                                                    const float* __restrict__ aev,
                                                    const int* __restrict__ seg,
                                                    float* __restrict__ h0out) {
    int s = blockIdx.y;
    int segend = seg[s + 1];
    int base = seg[s] + blockIdx.x * TILE;
    if (base >= segend) return;
    int n_act = min(TILE, segend - base);

    int t = threadIdx.x;
    int o = t >> 2, ks = t & 3;
    const float* Wr = W0 + (size_t)(s * H0 + o) * W0_PITCH + ks * 4;
    float bias = b0[s * H0 + o];
    float acc[TILE];
#pragma unroll
    for (int q = 0; q < TILE; q++) acc[q] = 0.f;

#pragma unroll
    for (int i = 0; i < NFEAT / 16; i++) {          // 7 iters, 16 floats per i
        float4 w = *(const float4*)(Wr + i * 16);
#pragma unroll
        for (int q = 0; q < TILE; q++) {
            float4 a = *(const float4*)(aev + (size_t)(base + q) * NFEAT + i * 16 + ks * 4);
            acc[q] += w.x*a.x + w.y*a.y + w.z*a.z + w.w*a.w;
        }
    }
#pragma unroll
    for (int q = 0; q < TILE; q++) {
        float v = acc[q];
        v += __shfl_xor(v, 1);
        v += __shfl_xor(v, 2);
        if (ks == 0 && q < n_act)
            h0out[(size_t)(base + q) * H0 + o] = celu01(v + bias);
    }
}

// ---------------- K2b: layer1  h0[256] -> h1[192], 768 thr ----------------
__global__ __launch_bounds__(768) void mlp1_kernel(const float* __restrict__ W1,
                                                   const float* __restrict__ b1,
                                                   const float* __restrict__ h0,
                                                   const int* __restrict__ seg,
                                                   float* __restrict__ h1out) {
    int s = blockIdx.y;
    int segend = seg[s + 1];
    int base = seg[s] + blockIdx.x * TILE;
    if (base >= segend) return;
    int n_act = min(TILE, segend - base);

    int t = threadIdx.x;
    int o = t >> 2, ks = t & 3;
    const float* Wr = W1 + (size_t)(s * H1 + o) * H0 + ks * 4;
    float bias = b1[s * H1 + o];
    float acc[TILE];
#pragma unroll
    for (int q = 0; q < TILE; q++) acc[q] = 0.f;

#pragma unroll 4
    for (int i = 0; i < H0 / 16; i++) {             // 16 iters
        float4 w = *(const float4*)(Wr + i * 16);
#pragma unroll
        for (int q = 0; q < TILE; q++) {
            float4 a = *(const float4*)(h0 + (size_t)(base + q) * H0 + i * 16 + ks * 4);
            acc[q] += w.x*a.x + w.y*a.y + w.z*a.z + w.w*a.w;
        }
    }
#pragma unroll
    for (int q = 0; q < TILE; q++) {
        float v = acc[q];
        v += __shfl_xor(v, 1);
        v += __shfl_xor(v, 2);
        if (ks == 0 && q < n_act)
            h1out[(size_t)(base + q) * H1 + o] = celu01(v + bias);
    }
}

// ---------------- K2c: layer2 + final dot + energy, 640 thr ----------------
__global__ __launch_bounds__(640) void mlp2_kernel(const float* __restrict__ W2,
                                                   const float* __restrict__ b2,
                                                   const float* __restrict__ Wf,
                                                   const float* __restrict__ bf,
                                                   const float* __restrict__ h1,
                                                   const int* __restrict__ seg,
                                                   float* __restrict__ out) {
    __shared__ float bsum;
    int s = blockIdx.y;
    int segend = seg[s + 1];
    int base = seg[s] + blockIdx.x * TILE;
    if (base >= segend) return;
    int n_act = min(TILE, segend - base);

    int t = threadIdx.x;
    if (t == 0) bsum = 0.f;
    __syncthreads();

    int o = t >> 2, ks = t & 3;
    const float* Wr = W2 + (size_t)(s * H2 + o) * H1 + ks * 4;
    float bias = b2[s * H2 + o];
    float wf = Wf[s * H2 + o];
    float acc[TILE];
#pragma unroll
    for (int q = 0; q < TILE; q++) acc[q] = 0.f;

#pragma unroll 4
    for (int i = 0; i < H1 / 16; i++) {             // 12 iters
        float4 w = *(const float4*)(Wr + i * 16);
#pragma unroll
        for (int q = 0; q < TILE; q++) {
            float4 a = *(const float4*)(h1 + (size_t)(base + q) * H1 + i * 16 + ks * 4);
            acc[q] += w.x*a.x + w.y*a.y + w.z*a.z + w.w*a.w;
        }
    }
    float contrib = 0.f;
#pragma unroll
    for (int q = 0; q < TILE; q++) {
        float v = acc[q];
        v += __shfl_xor(v, 1);
        v += __shfl_xor(v, 2);
        if (ks == 0 && q < n_act) contrib += wf * celu01(v + bias);
    }
    if (t == 0) contrib += (float)n_act * bf[s];    // final-layer bias, once per atom

    float v = contrib;
    v += __shfl_down(v, 32);
    v += __shfl_down(v, 16);
    v += __shfl_down(v, 8);
    v += __shfl_down(v, 4);
    v += __shfl_down(v, 2);
    v += __shfl_down(v, 1);
    if ((t & 63) == 0) atomicAdd(&bsum, v);
    __syncthreads();
    if (t == 0) atomicAdd(out, bsum);
}

extern "C" void kernel_launch(void* const* d_in, const int* in_sizes, int n_in,
                              void* d_out, int out_size, void* d_ws, size_t ws_size,
                              hipStream_t stream) {
    const int*   species = (const int*)d_in[0];
    const float* coords  = (const float*)d_in[1];
    const float* EtaR    = (const float*)d_in[2];
    const float* ShfR    = (const float*)d_in[3];
    const float* W0      = (const float*)d_in[4];
    const float* b0      = (const float*)d_in[5];
    const float* W1      = (const float*)d_in[6];
    const float* b1      = (const float*)d_in[7];
    const float* W2      = (const float*)d_in[8];
    const float* b2      = (const float*)d_in[9];
    const float* Wf      = (const float*)d_in[10];
    const float* bf      = (const float*)d_in[11];
    float* out = (float*)d_out;
    char* ws = (char*)d_ws;

    int*    seg    = (int*)(ws + WS_SEG);
    float4* scoord = (float4*)(ws + WS_SCOORD);
    float*  aev    = (float*)(ws + WS_AEV);
    float*  h0buf  = (float*)(ws + WS_H0BUF);
    float*  h1buf  = (float*)(ws + WS_H1BUF);

    hipLaunchKernelGGL(sort_kernel, dim3(1), dim3(256), 0, stream,
                       species, coords, seg, scoord, out);
    hipLaunchKernelGGL(aev_kernel, dim3(N_ATOMS / 4, NSPEC), dim3(256), 0, stream,
                       scoord, seg, ShfR, EtaR, aev);
    hipLaunchKernelGGL(mlp0_kernel, dim3(NTILES, NSPEC), dim3(1024), 0, stream,
                       W0, b0, aev, seg, h0buf);
    hipLaunchKernelGGL(mlp1_kernel, dim3(NTILES, NSPEC), dim3(768), 0, stream,
                       W1, b1, h0buf, seg, h1buf);
    hipLaunchKernelGGL(mlp2_kernel, dim3(NTILES, NSPEC), dim3(640), 0, stream,
                       W2, b2, Wf, bf, h1buf, seg, out);
}

// Round 7
// 157.290 us; speedup vs baseline: 1.5420x; 1.5420x over previous
//
#include <hip/hip_runtime.h>

#define N_ATOMS 2048
#define NSPEC 7
#define NR 16
#define NFEAT 112          // 7 species * 16 radial shifts; rest of 1008 is zero padding
#define K0P 128            // aev rows padded 112 -> 128 bf16 for MFMA K
#define RCR_F 5.2f
#define H0 256
#define H1 192
#define H2 160
#define W0_PITCH 1008
#define NTILE16 128        // max 16-atom m-tiles per species (worst case 2048/16)
#define GY2 (H2 / 16)      // 10 n-tiles in final layer
#define NPART (NSPEC * GY2 * NTILE16)   // 8960 partial energies

typedef __attribute__((ext_vector_type(8))) short short8;   // 8 bf16 (4 VGPRs)
typedef __attribute__((ext_vector_type(4))) float floatx4;  // MFMA accumulator

// ---- workspace layout (byte offsets into d_ws; poisoned 0xAA each call) ----
// act buffers get 2064 rows (16-row slack for m-tile tails; poisoned reads are
// finite bf16 and masked on store)
#define WS_SEG     0          // int[8]
#define WS_SCOORD  16384      // float4[2048]
#define WS_AEVB    65536      // ushort[2064*128]  bf16, ends 593920
#define WS_H0B     655360     // ushort[2064*256]  ends 1712128
#define WS_H1B     1769472    // ushort[2064*192]  ends 2562048
#define WS_WB0     2621440    // ushort[7*256*128] ends 3080192
#define WS_WB1     3145728    // ushort[7*192*256] ends 3833856
#define WS_WB2     3866624    // ushort[7*160*192] ends 4296704
#define WS_PART    4325376    // float[8960]

__device__ __forceinline__ float celu01(float x) {
    return x > 0.f ? x : 0.1f * (__expf(x * 10.f) - 1.f);
}

__device__ __forceinline__ unsigned short f2bf(float x) {   // RNE fp32 -> bf16
    unsigned int u = __float_as_uint(x);
    u = (u + 0x7FFFu + ((u >> 16) & 1u)) >> 16;
    return (unsigned short)u;
}

// ---------------- K0: counting sort by species + init ----------------
__global__ __launch_bounds__(256) void sort_kernel(const int* __restrict__ species,
                                                   const float* __restrict__ coords,
                                                   int* __restrict__ seg,
                                                   float4* __restrict__ scoord,
                                                   float* __restrict__ out) {
    __shared__ int cnt[NSPEC];
    __shared__ int cur[NSPEC];
    int t = threadIdx.x;
    if (t < NSPEC) cnt[t] = 0;
    __syncthreads();
    for (int a = t; a < N_ATOMS; a += 256) atomicAdd(&cnt[species[a]], 1);
    __syncthreads();
    if (t == 0) {
        int run = 0;
        for (int s = 0; s < NSPEC; s++) { seg[s] = run; cur[s] = run; run += cnt[s]; }
        seg[NSPEC] = run;
        out[0] = 0.0f;
    }
    __syncthreads();
    for (int a = t; a < N_ATOMS; a += 256) {
        int sp = species[a];
        int pos = atomicAdd(&cur[sp], 1);
        scoord[pos] = make_float4(coords[3*a], coords[3*a+1], coords[3*a+2], 0.f);
    }
}

// ---------------- K0b: weight fp32 -> bf16 prep ----------------
// Wb0[s][o][k<128] (k>=112 zero), Wb1[s][o][k<256], Wb2[s][o][k<192]
#define S0E (NSPEC * H0 * K0P)     // 229376
#define S1E (NSPEC * H1 * H0)      // 344064
#define S2E (NSPEC * H2 * H1)      // 215040
__global__ __launch_bounds__(256) void prep_kernel(const float* __restrict__ W0,
                                                   const float* __restrict__ W1,
                                                   const float* __restrict__ W2,
                                                   unsigned short* __restrict__ wb0,
                                                   unsigned short* __restrict__ wb1,
                                                   unsigned short* __restrict__ wb2) {
    int idx = blockIdx.x * 256 + threadIdx.x;
    if (idx < S0E) {
        int k = idx & 127, r = idx >> 7;            // r = s*256 + o
        float v = (k < NFEAT) ? W0[(size_t)r * W0_PITCH + k] : 0.f;
        wb0[idx] = f2bf(v);
    } else if (idx < S0E + S1E) {
        int j = idx - S0E;
        wb1[j] = f2bf(W1[j]);                       // same [s][o][k] layout, K=256
    } else if (idx < S0E + S1E + S2E) {
        int j = idx - S0E - S1E;
        wb2[j] = f2bf(W2[j]);                       // K=192
    }
}

// ---------------- K1: pair-parallel radial AEV -> bf16 rows of 128 ----------------
__global__ __launch_bounds__(256) void aev_kernel(const float4* __restrict__ scoord,
                                                  const int* __restrict__ seg,
                                                  const float* __restrict__ ShfR,
                                                  const float* __restrict__ EtaR,
                                                  unsigned short* __restrict__ aevb) {
    int s = blockIdx.y;
    int p = blockIdx.x * 4 + (threadIdx.x >> 6);
    int lane = threadIdx.x & 63;

    float4 ci = scoord[p];
    float eta = EtaR[0];
    float shf[NR];
#pragma unroll
    for (int r = 0; r < NR; r++) shf[r] = ShfR[r];
    float acc[NR];
#pragma unroll
    for (int r = 0; r < NR; r++) acc[r] = 0.f;

    int kbeg = seg[s] + lane;
    int kend = seg[s + 1];
    const float rc2 = RCR_F * RCR_F;
    const float cosk = 3.14159265358979f / RCR_F;

    for (int k = kbeg; k < kend; k += 64) {
        float4 cj = scoord[k];
        float dx = ci.x - cj.x, dy = ci.y - cj.y, dz = ci.z - cj.z;
        float dsq = dx*dx + dy*dy + dz*dz;
        bool valid = (dsq > 0.f) && (dsq <= rc2);
        float d = sqrtf(dsq);
        float fc = 0.5f * __cosf(d * cosk) + 0.5f;
        fc = valid ? fc : 0.f;
#pragma unroll
        for (int r = 0; r < NR; r++) {
            float u = d - shf[r];
            acc[r] = fmaf(__expf(-eta * u * u), fc, acc[r]);
        }
    }
#pragma unroll
    for (int r = 0; r < NR; r++) {
        float v = acc[r];
        v += __shfl_xor(v, 1);
        v += __shfl_xor(v, 2);
        v += __shfl_xor(v, 4);
        v += __shfl_xor(v, 8);
        v += __shfl_xor(v, 16);
        v += __shfl_xor(v, 32);
        acc[r] = v;
    }
    if (lane == 0) {
        unsigned short* dst = aevb + (size_t)p * K0P + s * NR;
#pragma unroll
        for (int r = 0; r < NR; r++) dst[r] = f2bf(acc[r]);
        if (s == 0) {   // zero the K pad [112,128) once per atom
            unsigned short* pz = aevb + (size_t)p * K0P + NFEAT;
#pragma unroll
            for (int r = 0; r < K0P - NFEAT; r++) pz[r] = 0;
        }
    }
}

// ---------------- MFMA dense layer: one wave per 16-atom x 16-output tile ----
// A[m=lane&15][k=quad*8+j], B[n=lane&15][k=quad*8+j], D col=lane&15,
// row=quad*4+reg (m89/m101-verified mapping). fp32 accumulate, celu epilogue,
// bf16 store masked to valid atoms.
template<int KSTEPS, int KP, int NTOT, int NPOUT>
__global__ __launch_bounds__(64) void mfma_layer(const unsigned short* __restrict__ act,
                                                 const unsigned short* __restrict__ wb,
                                                 const float* __restrict__ bias,
                                                 const int* __restrict__ seg,
                                                 unsigned short* __restrict__ outbuf) {
    int s = blockIdx.z;
    int segend = seg[s + 1];
    int base = seg[s] + blockIdx.x * 16;
    if (base >= segend) return;
    int nbase = blockIdx.y * 16;

    int lane = threadIdx.x;
    int r = lane & 15, quad = lane >> 4;

    const unsigned short* arow = act + (size_t)(base + r) * KP + quad * 8;
    const unsigned short* brow = wb + ((size_t)(s * NTOT + nbase + r)) * KP + quad * 8;

    floatx4 acc = {0.f, 0.f, 0.f, 0.f};
#pragma unroll
    for (int ks = 0; ks < KSTEPS; ks++) {
        short8 a = *(const short8*)(arow + ks * 32);
        short8 b = *(const short8*)(brow + ks * 32);
        acc = __builtin_amdgcn_mfma_f32_16x16x32_bf16(a, b, acc, 0, 0, 0);
    }
    float bi = bias[s * NTOT + nbase + r];
#pragma unroll
    for (int reg = 0; reg < 4; reg++) {
        int atom = base + quad * 4 + reg;
        if (atom < segend)
            outbuf[(size_t)atom * NPOUT + nbase + r] = f2bf(celu01(acc[reg] + bi));
    }
}

// ---------------- final layer: MFMA + wf dot + per-wave partial ----------------
__global__ __launch_bounds__(64) void mfma_final(const unsigned short* __restrict__ act,
                                                 const unsigned short* __restrict__ wb,
                                                 const float* __restrict__ bias,
                                                 const float* __restrict__ Wf,
                                                 const int* __restrict__ seg,
                                                 float* __restrict__ part) {
    int s = blockIdx.z;
    int pidx = (s * GY2 + blockIdx.y) * NTILE16 + blockIdx.x;
    int segend = seg[s + 1];
    int base = seg[s] + blockIdx.x * 16;
    int lane = threadIdx.x;
    if (base >= segend) {                 // inactive: part buffer is poisoned, zero it
        if (lane == 0) part[pidx] = 0.f;
        return;
    }
    int nbase = blockIdx.y * 16;
    int r = lane & 15, quad = lane >> 4;

    const unsigned short* arow = act + (size_t)(base + r) * H1 + quad * 8;
    const unsigned short* brow = wb + ((size_t)(s * H2 + nbase + r)) * H1 + quad * 8;

    floatx4 acc = {0.f, 0.f, 0.f, 0.f};
#pragma unroll
    for (int ks = 0; ks < H1 / 32; ks++) {    // 6 k-steps
        short8 a = *(const short8*)(arow + ks * 32);
        short8 b = *(const short8*)(brow + ks * 32);
        acc = __builtin_amdgcn_mfma_f32_16x16x32_bf16(a, b, acc, 0, 0, 0);
    }
    float bi = bias[s * H2 + nbase + r];
    float wf = Wf[s * H2 + nbase + r];
    float e = 0.f;
#pragma unroll
    for (int reg = 0; reg < 4; reg++) {
        int atom = base + quad * 4 + reg;
        if (atom < segend) e += wf * celu01(acc[reg] + bi);
    }
    // full-wave sum (each (atom, output) cell appears exactly once in the wave)
    e += __shfl_xor(e, 1);
    e += __shfl_xor(e, 2);
    e += __shfl_xor(e, 4);
    e += __shfl_xor(e, 8);
    e += __shfl_xor(e, 16);
    e += __shfl_xor(e, 32);
    if (lane == 0) part[pidx] = e;
}

// ---------------- final reduce: sum partials + final-layer biases ----------------
__global__ __launch_bounds__(256) void reduce_kernel(const float* __restrict__ part,
                                                     const int* __restrict__ seg,
                                                     const float* __restrict__ bf,
                                                     float* __restrict__ out) {
    __shared__ float wsum[4];
    int t = threadIdx.x;
    float v = 0.f;
    for (int i = t; i < NPART; i += 256) v += part[i];
    v += __shfl_down(v, 32);
    v += __shfl_down(v, 16);
    v += __shfl_down(v, 8);
    v += __shfl_down(v, 4);
    v += __shfl_down(v, 2);
    v += __shfl_down(v, 1);
    if ((t & 63) == 0) wsum[t >> 6] = v;
    __syncthreads();
    if (t == 0) {
        float tot = wsum[0] + wsum[1] + wsum[2] + wsum[3];
        for (int s = 0; s < NSPEC; s++) tot += (float)(seg[s + 1] - seg[s]) * bf[s];
        out[0] = tot;
    }
}

extern "C" void kernel_launch(void* const* d_in, const int* in_sizes, int n_in,
                              void* d_out, int out_size, void* d_ws, size_t ws_size,
                              hipStream_t stream) {
    const int*   species = (const int*)d_in[0];
    const float* coords  = (const float*)d_in[1];
    const float* EtaR    = (const float*)d_in[2];
    const float* ShfR    = (const float*)d_in[3];
    const float* W0      = (const float*)d_in[4];
    const float* b0      = (const float*)d_in[5];
    const float* W1      = (const float*)d_in[6];
    const float* b1      = (const float*)d_in[7];
    const float* W2      = (const float*)d_in[8];
    const float* b2      = (const float*)d_in[9];
    const float* Wf      = (const float*)d_in[10];
    const float* bf      = (const float*)d_in[11];
    float* out = (float*)d_out;
    char* ws = (char*)d_ws;

    int*            seg    = (int*)(ws + WS_SEG);
    float4*         scoord = (float4*)(ws + WS_SCOORD);
    unsigned short* aevb   = (unsigned short*)(ws + WS_AEVB);
    unsigned short* h0b    = (unsigned short*)(ws + WS_H0B);
    unsigned short* h1b    = (unsigned short*)(ws + WS_H1B);
    unsigned short* wb0    = (unsigned short*)(ws + WS_WB0);
    unsigned short* wb1    = (unsigned short*)(ws + WS_WB1);
    unsigned short* wb2    = (unsigned short*)(ws + WS_WB2);
    float*          part   = (float*)(ws + WS_PART);

    hipLaunchKernelGGL(sort_kernel, dim3(1), dim3(256), 0, stream,
                       species, coords, seg, scoord, out);
    hipLaunchKernelGGL(prep_kernel, dim3((S0E + S1E + S2E + 255) / 256), dim3(256), 0, stream,
                       W0, W1, W2, wb0, wb1, wb2);
    hipLaunchKernelGGL(aev_kernel, dim3(N_ATOMS / 4, NSPEC), dim3(256), 0, stream,
                       scoord, seg, ShfR, EtaR, aevb);
    hipLaunchKernelGGL((mfma_layer<K0P / 32, K0P, H0, H0>), dim3(NTILE16, H0 / 16, NSPEC),
                       dim3(64), 0, stream, aevb, wb0, b0, seg, h0b);
    hipLaunchKernelGGL((mfma_layer<H0 / 32, H0, H1, H1>), dim3(NTILE16, H1 / 16, NSPEC),
                       dim3(64), 0, stream, h0b, wb1, b1, seg, h1b);
    hipLaunchKernelGGL(mfma_final, dim3(NTILE16, GY2, NSPEC), dim3(64), 0, stream,
                       h1b, wb2, b2, Wf, seg, part);
    hipLaunchKernelGGL(reduce_kernel, dim3(1), dim3(256), 0, stream,
                       part, seg, bf, out);
}

// Round 8
// 133.873 us; speedup vs baseline: 1.8117x; 1.1749x over previous
//
#include <hip/hip_runtime.h>

#define N_ATOMS 2048
#define NSPEC 7
#define NR 16
#define NFEAT 112          // 7 species * 16 radial shifts; rest of 1008 is zero padding
#define K0P 128            // aev rows padded 112 -> 128 bf16 for MFMA K
#define RCR_F 5.2f
#define H0 256
#define H1 192
#define H2 160
#define W0_PITCH 1008
#define MT 16              // atoms per MLP block (one MFMA m-tile)
#define NTILE16 (N_ATOMS / MT)   // 128 worst-case m-tiles per species

typedef __attribute__((ext_vector_type(8))) short short8;   // 8 bf16 (4 VGPRs)
typedef __attribute__((ext_vector_type(4))) float floatx4;  // MFMA accumulator

// ---- workspace layout (byte offsets into d_ws; poisoned 0xAA each call) ----
// aevb has 2064 rows (16-row slack for m-tile tails; poisoned reads are finite
// bf16 ~ -3e-13 and masked in the energy epilogue)
#define WS_SEG     0          // int[8]
#define WS_SCOORD  16384      // float4[2048]
#define WS_AEVB    65536      // ushort[2064*128]  ends 593920
#define WS_WB0     2621440    // ushort[7*256*128]
#define WS_WB1     3145728    // ushort[7*192*256]
#define WS_WB2     3866624    // ushort[7*160*192]

#define S0E (NSPEC * H0 * K0P)     // 229376
#define S1E (NSPEC * H1 * H0)      // 344064
#define S2E (NSPEC * H2 * H1)      // 215040
#define PREP_TOT (S0E + S1E + S2E) // 788480 = 3080 * 256 exactly

__device__ __forceinline__ float celu01(float x) {
    return x > 0.f ? x : 0.1f * (__expf(x * 10.f) - 1.f);
}

__device__ __forceinline__ unsigned short f2bf(float x) {   // RNE fp32 -> bf16
    unsigned int u = __float_as_uint(x);
    u = (u + 0x7FFFu + ((u >> 16) & 1u)) >> 16;
    return (unsigned short)u;
}

// ---------------- K0: block 0 = counting sort; blocks 1.. = weight bf16 prep ----
__global__ __launch_bounds__(256) void setup_kernel(const int* __restrict__ species,
                                                    const float* __restrict__ coords,
                                                    const float* __restrict__ W0,
                                                    const float* __restrict__ W1,
                                                    const float* __restrict__ W2,
                                                    int* __restrict__ seg,
                                                    float4* __restrict__ scoord,
                                                    unsigned short* __restrict__ wb0,
                                                    unsigned short* __restrict__ wb1,
                                                    unsigned short* __restrict__ wb2,
                                                    float* __restrict__ out) {
    int t = threadIdx.x;
    if (blockIdx.x == 0) {
        __shared__ int cnt[NSPEC];
        __shared__ int cur[NSPEC];
        if (t < NSPEC) cnt[t] = 0;
        __syncthreads();
        for (int a = t; a < N_ATOMS; a += 256) atomicAdd(&cnt[species[a]], 1);
        __syncthreads();
        if (t == 0) {
            int run = 0;
            for (int s = 0; s < NSPEC; s++) { seg[s] = run; cur[s] = run; run += cnt[s]; }
            seg[NSPEC] = run;
            out[0] = 0.0f;   // d_out is poisoned before every call
        }
        __syncthreads();
        for (int a = t; a < N_ATOMS; a += 256) {
            int sp = species[a];
            int pos = atomicAdd(&cur[sp], 1);
            scoord[pos] = make_float4(coords[3*a], coords[3*a+1], coords[3*a+2], 0.f);
        }
    } else {
        int idx = (blockIdx.x - 1) * 256 + t;
        if (idx < S0E) {
            int k = idx & 127, r = idx >> 7;        // r = s*256 + o
            float v = (k < NFEAT) ? W0[(size_t)r * W0_PITCH + k] : 0.f;
            wb0[idx] = f2bf(v);
        } else if (idx < S0E + S1E) {
            wb1[idx - S0E] = f2bf(W1[idx - S0E]);
        } else {
            wb2[idx - S0E - S1E] = f2bf(W2[idx - S0E - S1E]);
        }
    }
}

// ---------------- K1: pair-parallel radial AEV -> bf16 rows of 128 ----------------
__global__ __launch_bounds__(256) void aev_kernel(const float4* __restrict__ scoord,
                                                  const int* __restrict__ seg,
                                                  const float* __restrict__ ShfR,
                                                  const float* __restrict__ EtaR,
                                                  unsigned short* __restrict__ aevb) {
    int s = blockIdx.y;
    int p = blockIdx.x * 4 + (threadIdx.x >> 6);
    int lane = threadIdx.x & 63;

    float4 ci = scoord[p];
    float eta = EtaR[0];
    float shf[NR];
#pragma unroll
    for (int r = 0; r < NR; r++) shf[r] = ShfR[r];
    float acc[NR];
#pragma unroll
    for (int r = 0; r < NR; r++) acc[r] = 0.f;

    int kbeg = seg[s] + lane;
    int kend = seg[s + 1];
    const float rc2 = RCR_F * RCR_F;
    const float cosk = 3.14159265358979f / RCR_F;

    for (int k = kbeg; k < kend; k += 64) {
        float4 cj = scoord[k];
        float dx = ci.x - cj.x, dy = ci.y - cj.y, dz = ci.z - cj.z;
        float dsq = dx*dx + dy*dy + dz*dz;
        bool valid = (dsq > 0.f) && (dsq <= rc2);
        float d = sqrtf(dsq);
        float fc = 0.5f * __cosf(d * cosk) + 0.5f;
        fc = valid ? fc : 0.f;
#pragma unroll
        for (int r = 0; r < NR; r++) {
            float u = d - shf[r];
            acc[r] = fmaf(__expf(-eta * u * u), fc, acc[r]);
        }
    }
#pragma unroll
    for (int r = 0; r < NR; r++) {
        float v = acc[r];
        v += __shfl_xor(v, 1);
        v += __shfl_xor(v, 2);
        v += __shfl_xor(v, 4);
        v += __shfl_xor(v, 8);
        v += __shfl_xor(v, 16);
        v += __shfl_xor(v, 32);
        acc[r] = v;
    }
    if (lane == 0) {
        unsigned short* dst = aevb + (size_t)p * K0P + s * NR;
#pragma unroll
        for (int r = 0; r < NR; r++) dst[r] = f2bf(acc[r]);
        if (s == 0) {
            unsigned short* pz = aevb + (size_t)p * K0P + NFEAT;
#pragma unroll
            for (int r = 0; r < K0P - NFEAT; r++) pz[r] = 0;
        }
    }
}

// ---------------- K2: fused 3-layer MFMA MLP + energy, one block = 16 atoms ----
// Grid (NTILE16, NSPEC), 256 threads = 4 waves. Wave w handles n-tiles
// nt = it*4+w of each layer. A-frags from LDS ([16][K+8] padded rows, 16B
// aligned); B (weights, bf16) streamed from global/L2. MFMA mappings per
// m89/m101: A[m=lane&15][k=quad*8+j], B[n=lane&15][k=...], D col=lane&15,
// row=quad*4+reg. Activations never touch global; energy via 4 atomicAdds.
__global__ __launch_bounds__(256) void mlp_fused(const unsigned short* __restrict__ aevb,
                                                 const unsigned short* __restrict__ wb0,
                                                 const unsigned short* __restrict__ wb1,
                                                 const unsigned short* __restrict__ wb2,
                                                 const float* __restrict__ b0,
                                                 const float* __restrict__ b1,
                                                 const float* __restrict__ b2,
                                                 const float* __restrict__ Wf,
                                                 const float* __restrict__ bf,
                                                 const int* __restrict__ seg,
                                                 float* __restrict__ out) {
    __shared__ unsigned short aevs[MT][K0P + 8];   // rows 272B (17x16B aligned)
    __shared__ unsigned short h0s[MT][H0 + 8];     // rows 528B
    __shared__ unsigned short h1s[MT][H1 + 8];     // rows 400B

    int s = blockIdx.z * 0 + blockIdx.y;           // species
    int segend = seg[s + 1];
    int base = seg[s] + blockIdx.x * MT;
    if (base >= segend) return;                    // block-uniform
    int n_act = min(MT, segend - base);

    int t = threadIdx.x;
    int w = t >> 6, lane = t & 63;
    int r = lane & 15, quad = lane >> 4;

    // ---- stage AEV tile: 256 threads x one 16B piece ----
    {
        int row = t >> 4, chunk = t & 15;          // 16 rows x 16 chunks of 8 shorts
        const short8* src = (const short8*)(aevb + (size_t)(base + row) * K0P + chunk * 8);
        *(short8*)&aevs[row][chunk * 8] = *src;
    }
    __syncthreads();

    // ---- layer0: aev[128] -> h0[256], 16 n-tiles over 4 waves ----
#pragma unroll
    for (int it = 0; it < 4; it++) {
        int nbase = (it * 4 + w) * 16;
        const unsigned short* brow = wb0 + ((size_t)(s * H0 + nbase + r)) * K0P + quad * 8;
        floatx4 acc = {0.f, 0.f, 0.f, 0.f};
#pragma unroll
        for (int ks = 0; ks < K0P / 32; ks++) {
            short8 a = *(const short8*)&aevs[r][ks * 32 + quad * 8];
            short8 b = *(const short8*)(brow + ks * 32);
            acc = __builtin_amdgcn_mfma_f32_16x16x32_bf16(a, b, acc, 0, 0, 0);
        }
        float bi = b0[s * H0 + nbase + r];
#pragma unroll
        for (int reg = 0; reg < 4; reg++)
            h0s[quad * 4 + reg][nbase + r] = f2bf(celu01(acc[reg] + bi));
    }
    __syncthreads();

    // ---- layer1: h0[256] -> h1[192], 12 n-tiles over 4 waves ----
#pragma unroll
    for (int it = 0; it < 3; it++) {
        int nbase = (it * 4 + w) * 16;
        const unsigned short* brow = wb1 + ((size_t)(s * H1 + nbase + r)) * H0 + quad * 8;
        floatx4 acc = {0.f, 0.f, 0.f, 0.f};
#pragma unroll
        for (int ks = 0; ks < H0 / 32; ks++) {
            short8 a = *(const short8*)&h0s[r][ks * 32 + quad * 8];
            short8 b = *(const short8*)(brow + ks * 32);
            acc = __builtin_amdgcn_mfma_f32_16x16x32_bf16(a, b, acc, 0, 0, 0);
        }
        float bi = b1[s * H1 + nbase + r];
#pragma unroll
        for (int reg = 0; reg < 4; reg++)
            h1s[quad * 4 + reg][nbase + r] = f2bf(celu01(acc[reg] + bi));
    }
    __syncthreads();

    // ---- layer2 + final dot: h1[192] -> 160 outputs, 10 n-tiles ----
    float e = 0.f;
#pragma unroll
    for (int it = 0; it < 3; it++) {
        int nt = it * 4 + w;
        if (nt >= H2 / 16) break;
        int nbase = nt * 16;
        const unsigned short* brow = wb2 + ((size_t)(s * H2 + nbase + r)) * H1 + quad * 8;
        floatx4 acc = {0.f, 0.f, 0.f, 0.f};
#pragma unroll
        for (int ks = 0; ks < H1 / 32; ks++) {
            short8 a = *(const short8*)&h1s[r][ks * 32 + quad * 8];
            short8 b = *(const short8*)(brow + ks * 32);
            acc = __builtin_amdgcn_mfma_f32_16x16x32_bf16(a, b, acc, 0, 0, 0);
        }
        float bi = b2[s * H2 + nbase + r];
        float wf = Wf[s * H2 + nbase + r];
#pragma unroll
        for (int reg = 0; reg < 4; reg++) {
            int atom = base + quad * 4 + reg;
            if (atom < segend) e += wf * celu01(acc[reg] + bi);
        }
    }
    if (t == 0) e += (float)n_act * bf[s];   // final-layer bias, once per atom

    // wave reduce, one atomic per wave (4/block)
    e += __shfl_xor(e, 1);
    e += __shfl_xor(e, 2);
    e += __shfl_xor(e, 4);
    e += __shfl_xor(e, 8);
    e += __shfl_xor(e, 16);
    e += __shfl_xor(e, 32);
    if (lane == 0) atomicAdd(out, e);
}

extern "C" void kernel_launch(void* const* d_in, const int* in_sizes, int n_in,
                              void* d_out, int out_size, void* d_ws, size_t ws_size,
                              hipStream_t stream) {
    const int*   species = (const int*)d_in[0];
    const float* coords  = (const float*)d_in[1];
    const float* EtaR    = (const float*)d_in[2];
    const float* ShfR    = (const float*)d_in[3];
    const float* W0      = (const float*)d_in[4];
    const float* b0      = (const float*)d_in[5];
    const float* W1      = (const float*)d_in[6];
    const float* b1      = (const float*)d_in[7];
    const float* W2      = (const float*)d_in[8];
    const float* b2      = (const float*)d_in[9];
    const float* Wf      = (const float*)d_in[10];
    const float* bf      = (const float*)d_in[11];
    float* out = (float*)d_out;
    char* ws = (char*)d_ws;

    int*            seg    = (int*)(ws + WS_SEG);
    float4*         scoord = (float4*)(ws + WS_SCOORD);
    unsigned short* aevb   = (unsigned short*)(ws + WS_AEVB);
    unsigned short* wb0    = (unsigned short*)(ws + WS_WB0);
    unsigned short* wb1    = (unsigned short*)(ws + WS_WB1);
    unsigned short* wb2    = (unsigned short*)(ws + WS_WB2);

    hipLaunchKernelGGL(setup_kernel, dim3(1 + PREP_TOT / 256), dim3(256), 0, stream,
                       species, coords, W0, W1, W2, seg, scoord, wb0, wb1, wb2, out);
    hipLaunchKernelGGL(aev_kernel, dim3(N_ATOMS / 4, NSPEC), dim3(256), 0, stream,
                       scoord, seg, ShfR, EtaR, aevb);
    hipLaunchKernelGGL(mlp_fused, dim3(NTILE16, NSPEC), dim3(256), 0, stream,
                       aevb, wb0, wb1, wb2, b0, b1, b2, Wf, bf, seg, out);
}

// Round 11
// 132.741 us; speedup vs baseline: 1.8272x; 1.0085x over previous
//
#include <hip/hip_runtime.h>

#define N_ATOMS 2048
#define NSPEC 7
#define NR 16
#define NFEAT 112          // 7 species * 16 radial shifts; rest of 1008 is zero padding
#define K0P 128            // aev rows padded 112 -> 128 bf16 for MFMA K
#define RCR_F 5.2f
#define H0 256
#define H1 192
#define H2 160
#define W0_PITCH 1008
#define MT 16              // atoms per MLP block (one MFMA m-tile)
#define NTILE16 (N_ATOMS / MT)   // 128 worst-case m-tiles per species

typedef __attribute__((ext_vector_type(8))) short short8;   // 8 bf16 (4 VGPRs)
typedef __attribute__((ext_vector_type(4))) float floatx4;  // MFMA accumulator

// ---- workspace layout (byte offsets into d_ws; poisoned 0xAA each call) ----
// aevb has 2064 rows (16-row slack for m-tile tails; poisoned reads are finite
// bf16 ~ -3e-13 and masked in the energy epilogue)
#define WS_SEG     0          // int[8]
#define WS_SCOORD  16384      // float4[2048]
#define WS_AEVB    65536      // ushort[2064*128]
#define WS_WB0     2621440    // ushort[7*256*128]
#define WS_WB1     3145728    // ushort[7*192*256]
#define WS_WB2     3866624    // ushort[7*160*192]

#define S0E (NSPEC * H0 * K0P)     // 229376
#define S1E (NSPEC * H1 * H0)      // 344064
#define S2E (NSPEC * H2 * H1)      // 215040
#define PREP_TOT (S0E + S1E + S2E) // 788480 = 3080 * 256 exactly

__device__ __forceinline__ float celu01(float x) {
    return x > 0.f ? x : 0.1f * (__expf(x * 10.f) - 1.f);
}

__device__ __forceinline__ unsigned short f2bf(float x) {   // RNE fp32 -> bf16
    unsigned int u = __float_as_uint(x);
    u = (u + 0x7FFFu + ((u >> 16) & 1u)) >> 16;
    return (unsigned short)u;
}

// ---------------- K0: block 0 = counting sort; blocks 1.. = weight bf16 prep ----
__global__ __launch_bounds__(256) void setup_kernel(const int* __restrict__ species,
                                                    const float* __restrict__ coords,
                                                    const float* __restrict__ W0,
                                                    const float* __restrict__ W1,
                                                    const float* __restrict__ W2,
                                                    int* __restrict__ seg,
                                                    float4* __restrict__ scoord,
                                                    unsigned short* __restrict__ wb0,
                                                    unsigned short* __restrict__ wb1,
                                                    unsigned short* __restrict__ wb2,
                                                    float* __restrict__ out) {
    int t = threadIdx.x;
    if (blockIdx.x == 0) {
        __shared__ int cnt[NSPEC];
        __shared__ int cur[NSPEC];
        if (t < NSPEC) cnt[t] = 0;
        __syncthreads();
        for (int a = t; a < N_ATOMS; a += 256) atomicAdd(&cnt[species[a]], 1);
        __syncthreads();
        if (t == 0) {
            int run = 0;
            for (int s = 0; s < NSPEC; s++) { seg[s] = run; cur[s] = run; run += cnt[s]; }
            seg[NSPEC] = run;
            out[0] = 0.0f;   // d_out is poisoned before every call
        }
        __syncthreads();
        for (int a = t; a < N_ATOMS; a += 256) {
            int sp = species[a];
            int pos = atomicAdd(&cur[sp], 1);
            scoord[pos] = make_float4(coords[3*a], coords[3*a+1], coords[3*a+2], 0.f);
        }
    } else {
        int idx = (blockIdx.x - 1) * 256 + t;
        if (idx < S0E) {
            int k = idx & 127, r = idx >> 7;        // r = s*256 + o
            float v = (k < NFEAT) ? W0[(size_t)r * W0_PITCH + k] : 0.f;
            wb0[idx] = f2bf(v);
        } else if (idx < S0E + S1E) {
            wb1[idx - S0E] = f2bf(W1[idx - S0E]);
        } else {
            wb2[idx - S0E - S1E] = f2bf(W2[idx - S0E - S1E]);
        }
    }
}

// ---------------- K1: pair-parallel radial AEV -> bf16 rows of 128 ----------------
// Grid (512, 7), 256 thr = 4 waves; wave w owns (atom p = bx*4+w, species by):
// 64 lanes walk the species segment lane-strided (coalesced), 16 independent
// exps per pair, 6-round butterfly, lane 0 writes 16 bf16. 14336 waves.
__global__ __launch_bounds__(256) void aev_kernel(const float4* __restrict__ scoord,
                                                  const int* __restrict__ seg,
                                                  const float* __restrict__ ShfR,
                                                  const float* __restrict__ EtaR,
                                                  unsigned short* __restrict__ aevb) {
    int s = blockIdx.y;
    int p = blockIdx.x * 4 + (threadIdx.x >> 6);
    int lane = threadIdx.x & 63;

    float4 ci = scoord[p];
    float eta = EtaR[0];
    float shf[NR];
#pragma unroll
    for (int r = 0; r < NR; r++) shf[r] = ShfR[r];
    float acc[NR];
#pragma unroll
    for (int r = 0; r < NR; r++) acc[r] = 0.f;

    int kbeg = seg[s] + lane;
    int kend = seg[s + 1];
    const float rc2 = RCR_F * RCR_F;
    const float cosk = 3.14159265358979f / RCR_F;

    for (int k = kbeg; k < kend; k += 64) {
        float4 cj = scoord[k];
        float dx = ci.x - cj.x, dy = ci.y - cj.y, dz = ci.z - cj.z;
        float dsq = dx*dx + dy*dy + dz*dz;
        bool valid = (dsq > 0.f) && (dsq <= rc2);
        float d = sqrtf(dsq);
        float fc = 0.5f * __cosf(d * cosk) + 0.5f;
        fc = valid ? fc : 0.f;
#pragma unroll
        for (int r = 0; r < NR; r++) {
            float u = d - shf[r];
            acc[r] = fmaf(__expf(-eta * u * u), fc, acc[r]);
        }
    }
#pragma unroll
    for (int r = 0; r < NR; r++) {
        float v = acc[r];
        v += __shfl_xor(v, 1);
        v += __shfl_xor(v, 2);
        v += __shfl_xor(v, 4);
        v += __shfl_xor(v, 8);
        v += __shfl_xor(v, 16);
        v += __shfl_xor(v, 32);
        acc[r] = v;
    }
    if (lane == 0) {
        unsigned short* dst = aevb + (size_t)p * K0P + s * NR;
#pragma unroll
        for (int r = 0; r < NR; r++) dst[r] = f2bf(acc[r]);
        if (s == 0) {
            unsigned short* pz = aevb + (size_t)p * K0P + NFEAT;
#pragma unroll
            for (int r = 0; r < K0P - NFEAT; r++) pz[r] = 0;
        }
    }
}

// ---------------- K2: fused 3-layer MFMA MLP + energy, one block = 16 atoms ----
// Grid (NTILE16, NSPEC), 256 threads = 4 waves. Wave w handles n-tiles
// nt = it*4+w of each layer. A-frags from LDS ([16][K+8] padded rows, 16B
// aligned); B (weights, bf16) streamed from global/L2. MFMA mappings per
// m89/m101: A[m=lane&15][k=quad*8+j], B[n=lane&15][k=...], D col=lane&15,
// row=quad*4+reg. Activations never touch global; energy via 4 atomicAdds.
__global__ __launch_bounds__(256) void mlp_fused(const unsigned short* __restrict__ aevb,
                                                 const unsigned short* __restrict__ wb0,
                                                 const unsigned short* __restrict__ wb1,
                                                 const unsigned short* __restrict__ wb2,
                                                 const float* __restrict__ b0,
                                                 const float* __restrict__ b1,
                                                 const float* __restrict__ b2,
                                                 const float* __restrict__ Wf,
                                                 const float* __restrict__ bf,
                                                 const int* __restrict__ seg,
                                                 float* __restrict__ out) {
    __shared__ unsigned short aevs[MT][K0P + 8];   // rows 272B (17x16B aligned)
    __shared__ unsigned short h0s[MT][H0 + 8];     // rows 528B
    __shared__ unsigned short h1s[MT][H1 + 8];     // rows 400B

    int s = blockIdx.y;                            // species
    int segend = seg[s + 1];
    int base = seg[s] + blockIdx.x * MT;
    if (base >= segend) return;                    // block-uniform
    int n_act = min(MT, segend - base);

    int t = threadIdx.x;
    int w = t >> 6, lane = t & 63;
    int r = lane & 15, quad = lane >> 4;

    // ---- stage AEV tile: 256 threads x one 16B piece ----
    {
        int row = t >> 4, chunk = t & 15;          // 16 rows x 16 chunks of 8 shorts
        const short8* src = (const short8*)(aevb + (size_t)(base + row) * K0P + chunk * 8);
        *(short8*)&aevs[row][chunk * 8] = *src;
    }
    __syncthreads();

    // ---- layer0: aev[128] -> h0[256], 16 n-tiles over 4 waves ----
#pragma unroll
    for (int it = 0; it < 4; it++) {
        int nbase = (it * 4 + w) * 16;
        const unsigned short* brow = wb0 + ((size_t)(s * H0 + nbase + r)) * K0P + quad * 8;
        floatx4 acc = {0.f, 0.f, 0.f, 0.f};
#pragma unroll
        for (int ks = 0; ks < K0P / 32; ks++) {
            short8 a = *(const short8*)&aevs[r][ks * 32 + quad * 8];
            short8 b = *(const short8*)(brow + ks * 32);
            acc = __builtin_amdgcn_mfma_f32_16x16x32_bf16(a, b, acc, 0, 0, 0);
        }
        float bi = b0[s * H0 + nbase + r];
#pragma unroll
        for (int reg = 0; reg < 4; reg++)
            h0s[quad * 4 + reg][nbase + r] = f2bf(celu01(acc[reg] + bi));
    }
    __syncthreads();

    // ---- layer1: h0[256] -> h1[192], 12 n-tiles over 4 waves ----
#pragma unroll
    for (int it = 0; it < 3; it++) {
        int nbase = (it * 4 + w) * 16;
        const unsigned short* brow = wb1 + ((size_t)(s * H1 + nbase + r)) * H0 + quad * 8;
        floatx4 acc = {0.f, 0.f, 0.f, 0.f};
#pragma unroll
        for (int ks = 0; ks < H0 / 32; ks++) {
            short8 a = *(const short8*)&h0s[r][ks * 32 + quad * 8];
            short8 b = *(const short8*)(brow + ks * 32);
            acc = __builtin_amdgcn_mfma_f32_16x16x32_bf16(a, b, acc, 0, 0, 0);
        }
        float bi = b1[s * H1 + nbase + r];
#pragma unroll
        for (int reg = 0; reg < 4; reg++)
            h1s[quad * 4 + reg][nbase + r] = f2bf(celu01(acc[reg] + bi));
    }
    __syncthreads();

    // ---- layer2 + final dot: h1[192] -> 160 outputs, 10 n-tiles ----
    float e = 0.f;
#pragma unroll
    for (int it = 0; it < 3; it++) {
        int nt = it * 4 + w;
        if (nt >= H2 / 16) break;
        int nbase = nt * 16;
        const unsigned short* brow = wb2 + ((size_t)(s * H2 + nbase + r)) * H1 + quad * 8;
        floatx4 acc = {0.f, 0.f, 0.f, 0.f};
#pragma unroll
        for (int ks = 0; ks < H1 / 32; ks++) {
            short8 a = *(const short8*)&h1s[r][ks * 32 + quad * 8];
            short8 b = *(const short8*)(brow + ks * 32);
            acc = __builtin_amdgcn_mfma_f32_16x16x32_bf16(a, b, acc, 0, 0, 0);
        }
        float bi = b2[s * H2 + nbase + r];
        float wf = Wf[s * H2 + nbase + r];
#pragma unroll
        for (int reg = 0; reg < 4; reg++) {
            int atom = base + quad * 4 + reg;
            if (atom < segend) e += wf * celu01(acc[reg] + bi);
        }
    }
    if (t == 0) e += (float)n_act * bf[s];   // final-layer bias, once per atom

    // wave reduce, one atomic per wave (4/block)
    e += __shfl_xor(e, 1);
    e += __shfl_xor(e, 2);
    e += __shfl_xor(e, 4);
    e += __shfl_xor(e, 8);
    e += __shfl_xor(e, 16);
    e += __shfl_xor(e, 32);
    if (lane == 0) atomicAdd(out, e);
}

extern "C" void kernel_launch(void* const* d_in, const int* in_sizes, int n_in,
                              void* d_out, int out_size, void* d_ws, size_t ws_size,
                              hipStream_t stream) {
    const int*   species = (const int*)d_in[0];
    const float* coords  = (const float*)d_in[1];
    const float* EtaR    = (const float*)d_in[2];
    const float* ShfR    = (const float*)d_in[3];
    const float* W0      = (const float*)d_in[4];
    const float* b0      = (const float*)d_in[5];
    const float* W1      = (const float*)d_in[6];
    const float* b1      = (const float*)d_in[7];
    const float* W2      = (const float*)d_in[8];
    const float* b2      = (const float*)d_in[9];
    const float* Wf      = (const float*)d_in[10];
    const float* bf      = (const float*)d_in[11];
    float* out = (float*)d_out;
    char* ws = (char*)d_ws;

    int*            seg    = (int*)(ws + WS_SEG);
    float4*         scoord = (float4*)(ws + WS_SCOORD);
    unsigned short* aevb   = (unsigned short*)(ws + WS_AEVB);
    unsigned short* wb0    = (unsigned short*)(ws + WS_WB0);
    unsigned short* wb1    = (unsigned short*)(ws + WS_WB1);
    unsigned short* wb2    = (unsigned short*)(ws + WS_WB2);

    hipLaunchKernelGGL(setup_kernel, dim3(1 + PREP_TOT / 256), dim3(256), 0, stream,
                       species, coords, W0, W1, W2, seg, scoord, wb0, wb1, wb2, out);
    hipLaunchKernelGGL(aev_kernel, dim3(N_ATOMS / 4, NSPEC), dim3(256), 0, stream,
                       scoord, seg, ShfR, EtaR, aevb);
    hipLaunchKernelGGL(mlp_fused, dim3(NTILE16, NSPEC), dim3(256), 0, stream,
                       aevb, wb0, wb1, wb2, b0, b1, b2, Wf, bf, seg, out);
}